// Round 1
// 486.991 us; speedup vs baseline: 1.0527x; 1.0527x over previous
//
#include <hip/hip_runtime.h>
#include <hip/hip_bf16.h>

// Problem constants (match reference)
#define BB 256
#define II 182
#define TT 2000
#define OO 2

// Fused kernel: one block per batch element b.
//   Phase 1: curr[o][t] = sum_i in[b][i][t] * W[o][i] + bias[o]  -> LDS (swizzled)
//   Phase 2: PARALLEL affine scan over t: waves 0/1 handle o=0/1, 64 lanes each,
//            chunk=32 steps/lane, shfl_up compose of (A,B,S,u,v) transforms.
//            Recurrence: syn_t = a*syn_{t-1} + c_t ; mem_t = bt*mem_{t-1} + syn_t
//            Chunk transform: syn_out = A*syn_in + u ; mem_out = S*syn_in + B*mem_in + v
//   Phase 3: cooperative coalesced float4 store of out[b][:][:]
// LDS planes use idx = t + t/32 swizzle: scan accesses (stride 32 floats) would be
// 64-way same-bank; swizzled they're 2 lanes/bank (free).
__global__ __launch_bounds__(512) void snn_fused_kernel(const float* __restrict__ in,
                                                        const float* __restrict__ W,
                                                        const float* __restrict__ bias,
                                                        const float* __restrict__ alpha,
                                                        const float* __restrict__ beta,
                                                        float* __restrict__ out) {
    __shared__ float w0[II];
    __shared__ float w1[II];
    __shared__ float curr_sw[OO][2064];   // swizzled [o][t + t/32], 16.5 KB
    __shared__ float mem_sw[OO][2064];    // swizzled [o][t + t/32], 16.5 KB

    const int b = blockIdx.x;
    const int tid = threadIdx.x;

    if (tid < II) {
        w0[tid] = W[tid];       // W[0][i]
        w1[tid] = W[II + tid];  // W[1][i]
    }
    __syncthreads();

    // ---- Phase 1: GEMM into LDS ----
    if (tid < TT / 4) {  // 500 active threads, each one float4 (4 consecutive t)
        const float4* p = (const float4*)(in + (size_t)b * II * TT) + tid;
        float4 a0 = {0.f, 0.f, 0.f, 0.f};
        float4 a1 = {0.f, 0.f, 0.f, 0.f};
#pragma unroll 7
        for (int i = 0; i < II; ++i) {
            const float4 x = p[i * (TT / 4)];
            const float wa = w0[i];
            const float wb = w1[i];
            a0.x += x.x * wa; a0.y += x.y * wa; a0.z += x.z * wa; a0.w += x.w * wa;
            a1.x += x.x * wb; a1.y += x.y * wb; a1.z += x.z * wb; a1.w += x.w * wb;
        }
        const float b0 = bias[0];
        const float b1 = bias[1];
        // t = tid*4 .. tid*4+3 all share the same t/32 group (4 | 32)
        const int base = tid * 4 + (tid >> 3);  // t + t/32
        curr_sw[0][base + 0] = a0.x + b0; curr_sw[0][base + 1] = a0.y + b0;
        curr_sw[0][base + 2] = a0.z + b0; curr_sw[0][base + 3] = a0.w + b0;
        curr_sw[1][base + 0] = a1.x + b1; curr_sw[1][base + 1] = a1.y + b1;
        curr_sw[1][base + 2] = a1.z + b1; curr_sw[1][base + 3] = a1.w + b1;
    }
    __syncthreads();

    // ---- Phase 2: wave-parallel affine scan (wave 0 -> o=0, wave 1 -> o=1) ----
    {
        const int wid = tid >> 6;
        const int lane = tid & 63;
        if (wid < OO) {
            const int o = wid;
            const float a  = fminf(fmaxf(alpha[o], 0.f), 1.f);
            const float bt = fminf(fmaxf(beta[o],  0.f), 1.f);
            const int t0 = lane * 32;       // this lane's chunk start
            const int ib = 33 * lane;       // swizzled base: t0 + t0/32

            // Pass 1: build chunk transform (A, B, S, u, v) with zero initial state.
            //   A_k = a^k ; B_k = bt^k ; S_k = bt*S_{k-1} + A_k
            //   u_k = a*u_{k-1} + c_k (particular syn) ; v_k = bt*v_{k-1} + u_k (particular mem)
            float A = 1.f, Bb = 1.f, S = 0.f, u = 0.f, v = 0.f;
#pragma unroll
            for (int k = 0; k < 32; ++k) {
                const float c = (t0 + k < TT) ? curr_sw[o][ib + k] : 0.f;
                A *= a;
                Bb *= bt;
                S = bt * S + A;
                u = a * u + c;
                v = bt * v + u;
            }

            // Inclusive Hillis-Steele scan of transform composition across 64 lanes.
            // compose(earlier=1, later=2):
            //   A=A2*A1; B=B2*B1; S=S2*A1+B2*S1; u=A2*u1+u2; v=S2*u1+B2*v1+v2
#pragma unroll
            for (int d = 1; d < 64; d <<= 1) {
                const float A1 = __shfl_up(A,  (unsigned)d, 64);
                const float B1 = __shfl_up(Bb, (unsigned)d, 64);
                const float S1 = __shfl_up(S,  (unsigned)d, 64);
                const float u1 = __shfl_up(u,  (unsigned)d, 64);
                const float v1 = __shfl_up(v,  (unsigned)d, 64);
                if (lane >= d) {
                    u  = A * u1 + u;                 // uses A (=A2) before update
                    v  = S * u1 + Bb * v1 + v;       // uses S,Bb (=S2,B2) before update
                    S  = S * A1 + Bb * S1;
                    A  = A * A1;
                    Bb = Bb * B1;
                }
            }

            // Exclusive carry: lane l's initial state = prefix (u,v) of lane l-1.
            float syn = __shfl_up(u, 1u, 64);
            float mem = __shfl_up(v, 1u, 64);
            if (lane == 0) { syn = 0.f; mem = 0.f; }

            // Pass 2: replay chunk with correct initial state (plain recurrence).
#pragma unroll
            for (int k = 0; k < 32; ++k) {
                if (t0 + k < TT) {
                    const float c = curr_sw[o][ib + k];
                    syn = a * syn + c;
                    mem = bt * mem + syn;
                    mem_sw[o][ib + k] = mem;
                }
            }
        }
    }
    __syncthreads();

    // ---- Phase 3: coalesced store of out[b][t][o] ----
    // 500 threads each handle 4 t's -> two float4 stores ({m0,m1} interleaved).
    if (tid < TT / 4) {
        const int base = tid * 4 + (tid >> 3);  // swizzled index of t = tid*4
        const float m00 = mem_sw[0][base + 0], m10 = mem_sw[1][base + 0];
        const float m01 = mem_sw[0][base + 1], m11 = mem_sw[1][base + 1];
        const float m02 = mem_sw[0][base + 2], m12 = mem_sw[1][base + 2];
        const float m03 = mem_sw[0][base + 3], m13 = mem_sw[1][base + 3];
        float4* o4 = (float4*)(out + (size_t)b * TT * OO + (size_t)tid * 8);
        o4[0] = make_float4(m00, m10, m01, m11);
        o4[1] = make_float4(m02, m12, m03, m13);
    }
}

extern "C" void kernel_launch(void* const* d_in, const int* in_sizes, int n_in,
                              void* d_out, int out_size, void* d_ws, size_t ws_size,
                              hipStream_t stream) {
    const float* inputs = (const float*)d_in[0];  // [B, I, T]
    const float* W      = (const float*)d_in[1];  // [O, I]
    const float* bias   = (const float*)d_in[2];  // [O]
    const float* alpha  = (const float*)d_in[3];  // [O]
    const float* beta   = (const float*)d_in[4];  // [O]
    float* out = (float*)d_out;                   // [B, T, O]

    snn_fused_kernel<<<BB, 512, 0, stream>>>(inputs, W, bias, alpha, beta, out);
}